// Round 9
// baseline (116.197 us; speedup 1.0000x reference)
//
#include <hip/hip_runtime.h>
#include <hip/hip_bf16.h>

#define HW 16384   // 128*128
#define CC 64
#define BB 4

typedef __attribute__((ext_vector_type(8))) short bf8;   // 8 bf16 (4 VGPRs)
typedef __attribute__((ext_vector_type(4))) float f4;    // MFMA C/D frag

static __device__ __forceinline__ unsigned short f2bf(float f) {
    __hip_bfloat16 h = __float2bfloat16(f);   // RNE
    return *reinterpret_cast<unsigned short*>(&h);
}
// low/high bf16 of a packed dword as fp32 (1 VALU op each)
static __device__ __forceinline__ float lo16f(unsigned u) { return __uint_as_float(u << 16); }
static __device__ __forceinline__ float hi16f(unsigned u) { return __uint_as_float(u & 0xFFFF0000u); }
// RNE-pack two fp32 -> bf16x2 dword (bit-identical to __float2bfloat16 for finite)
static __device__ __forceinline__ unsigned rne_pack(float flo, float fhi) {
    unsigned a = __float_as_uint(flo);
    unsigned b = __float_as_uint(fhi);
    a += 0x7FFFu + ((a >> 16) & 1u);
    b += 0x7FFFu + ((b >> 16) & 1u);
    return __builtin_amdgcn_perm(b, a, 0x07060302u);   // {b[3],b[2],a[3],a[2]}
}

// ---------------------------------------------------------------------------
// K0: weight repack (blocks 0..215) + x transpose via LDS (blocks 216..1239).
// (identical to the verified v7 version)
//  wA2 : wave-coalesced A-frags for the conv phase. group g = tap*4+h2*2+m2
//  Wal2: wave-coalesced A-frags for the align GEMM. g = (tap*2+h2)*4+mt
//  xT  [b*HW+hw][c] : channels contiguous (128B rows)
// ---------------------------------------------------------------------------
__global__ __launch_bounds__(256) void k_prep_tx(const float* __restrict__ x,
                                                 const float* __restrict__ w_off,
                                                 const float* __restrict__ w_align,
                                                 unsigned short* __restrict__ xT,
                                                 unsigned short* __restrict__ wA2,
                                                 unsigned short* __restrict__ Wal2) {
    __shared__ unsigned T32[64 * 33];   // 8448 B
    int bx = blockIdx.x, t = threadIdx.x;
    if (bx < 216) {
        int i = bx * 256 + t;
        if (i < 32 * 576) {             // 18432 elems -> wA2
            int jj = i & 7;
            int chunk = i >> 3;
            int l = chunk & 63;
            int g = chunk >> 6;         // 0..35 = tap*4 + h2*2 + m2
            int m2 = g & 1;
            int h2 = (g >> 1) & 1;
            int tp = g >> 2;            // tap 0..8
            int m = m2 * 16 + (l & 15);
            int c = h2 * 32 + (l >> 4) * 8 + jj;
            float v = (m < 27) ? w_off[m * 576 + c * 9 + tp] : 0.f;
            wA2[i] = f2bf(v);
        } else {
            int j = i - 32 * 576;       // 0..36863 = 72 groups x 64 lanes x 8
            int jj = j & 7;
            int chunk = j >> 3;
            int l = chunk & 63;
            int g = chunk >> 6;         // (tap*2+h2)*4 + mt
            int mt = g & 3;
            int th = g >> 2;
            int h2 = th & 1;
            int tp = th >> 1;           // tap 0..8
            int o = mt * 16 + (l & 15);
            int c = h2 * 32 + (l >> 4) * 8 + jj;
            Wal2[j] = f2bf(w_align[o * 576 + c * 9 + tp]);
        }
        return;
    }
    int pix0 = (bx - 216) * 64;
    int b = pix0 >> 14, hw0 = pix0 & (HW - 1);
    const float* xb = x + (size_t)b * CC * HW + hw0;
#pragma unroll
    for (int u = 0; u < 8; u++) {
        int i = t + 256 * u;                 // 2048 = 32 cp x 64 p
        int cp = i >> 6, p = i & 63;
        float v0 = xb[(size_t)(2 * cp) * HW + p];
        float v1 = xb[(size_t)(2 * cp + 1) * HW + p];
        T32[p * 33 + cp] = (unsigned)f2bf(v0) | ((unsigned)f2bf(v1) << 16);
    }
    __syncthreads();
#pragma unroll
    for (int u = 0; u < 2; u++) {
        int i = t + 256 * u;                 // 512 = 64 p x 8 q
        int p = i >> 3, q = i & 7;
        uint4 qq;
        qq.x = T32[p * 33 + q * 4 + 0];
        qq.y = T32[p * 33 + q * 4 + 1];
        qq.z = T32[p * 33 + q * 4 + 2];
        qq.w = T32[p * 33 + q * 4 + 3];
        *(uint4*)(xT + ((size_t)b * HW + hw0 + p) * CC + q * 8) = qq;
    }
}

// bilinear sample of one pixel's 64 channels (this lane: chunks quad, quad+4)
// -> two B-frags. EXACT v7 math/indexing; hp/wp parameterized.
static __device__ __forceinline__ void bilin_px(
    const unsigned short* __restrict__ TF, const unsigned short* __restrict__ xTb,
    float dy, float dx, float m, int hp, int wp, int k3, int kx,
    int hm2, int hp3, int wm3, int wp66, int quad, bf8* bfrag)
{
    float ys = (float)(hp + k3 - 1) + dy;
    float xs = (float)(wp + kx - 1) + dx;
    float y0f = floorf(ys), x0f = floorf(xs);
    float fy = ys - y0f, fx = xs - x0f;
    int y0 = (int)y0f, x0 = (int)x0f;
    int y1 = y0 + 1, x1 = x0 + 1;
    bool vy0 = (unsigned)y0 < 128u, vy1 = (unsigned)y1 < 128u;
    bool vx0 = (unsigned)x0 < 128u, vx1 = (unsigned)x1 < 128u;
    int cy0 = min(max(y0, 0), 127), cy1 = min(max(y1, 0), 127);
    int cx0 = min(max(x0, 0), 127), cx1 = min(max(x1, 0), 127);
    float w00 = (1.f - fy) * (1.f - fx) * ((vy0 && vx0) ? m : 0.f);
    float w01 = (1.f - fy) * fx         * ((vy0 && vx1) ? m : 0.f);
    float w10 = fy * (1.f - fx)         * ((vy1 && vx0) ? m : 0.f);
    float w11 = fy * fx                 * ((vy1 && vx1) ? m : 0.f);

    bool inT = (cy0 >= hm2) & (cy1 <= hp3) & (cx0 >= wm3) & (cx1 <= wp66);
    uint4 qa0, qa1, qa2, qa3, qb0, qb1, qb2, qb3;
    if (inT) {
        int r0 = (cy0 - hm2) * 70 - wm3, r1 = (cy1 - hm2) * 70 - wm3;
        int e00 = r0 + cx0, e01 = r0 + cx1, e10 = r1 + cx0, e11 = r1 + cx1;
        int s00 = quad ^ (e00 & 7), s01 = quad ^ (e01 & 7);
        int s10 = quad ^ (e10 & 7), s11 = quad ^ (e11 & 7);
        qa0 = *(const uint4*)(TF + e00 * 64 + (s00 << 3));
        qa1 = *(const uint4*)(TF + e01 * 64 + (s01 << 3));
        qa2 = *(const uint4*)(TF + e10 * 64 + (s10 << 3));
        qa3 = *(const uint4*)(TF + e11 * 64 + (s11 << 3));
        qb0 = *(const uint4*)(TF + e00 * 64 + ((s00 ^ 4) << 3));
        qb1 = *(const uint4*)(TF + e01 * 64 + ((s01 ^ 4) << 3));
        qb2 = *(const uint4*)(TF + e10 * 64 + ((s10 ^ 4) << 3));
        qb3 = *(const uint4*)(TF + e11 * 64 + ((s11 ^ 4) << 3));
    } else {
        const unsigned short* c00 = xTb + ((size_t)(cy0 * 128 + cx0)) * CC + quad * 8;
        const unsigned short* c01 = xTb + ((size_t)(cy0 * 128 + cx1)) * CC + quad * 8;
        const unsigned short* c10 = xTb + ((size_t)(cy1 * 128 + cx0)) * CC + quad * 8;
        const unsigned short* c11 = xTb + ((size_t)(cy1 * 128 + cx1)) * CC + quad * 8;
        qa0 = *(const uint4*)(c00);      qa1 = *(const uint4*)(c01);
        qa2 = *(const uint4*)(c10);      qa3 = *(const uint4*)(c11);
        qb0 = *(const uint4*)(c00 + 32); qb1 = *(const uint4*)(c01 + 32);
        qb2 = *(const uint4*)(c10 + 32); qb3 = *(const uint4*)(c11 + 32);
    }
#pragma unroll
    for (int h2 = 0; h2 < 2; h2++) {
        const unsigned* u0 = (const unsigned*)(h2 ? &qb0 : &qa0);
        const unsigned* u1 = (const unsigned*)(h2 ? &qb1 : &qa1);
        const unsigned* u2 = (const unsigned*)(h2 ? &qb2 : &qa2);
        const unsigned* u3 = (const unsigned*)(h2 ? &qb3 : &qa3);
        __align__(16) unsigned rr4[4];
#pragma unroll
        for (int d = 0; d < 4; d++) {
            unsigned p0 = u0[d], p1 = u1[d], p2 = u2[d], p3 = u3[d];
            float lo = w00 * lo16f(p0) + w01 * lo16f(p1)
                     + w10 * lo16f(p2) + w11 * lo16f(p3);
            float hi = w00 * hi16f(p0) + w01 * hi16f(p1)
                     + w10 * hi16f(p2) + w11 * hi16f(p3);
            rr4[d] = rne_pack(lo, hi);
        }
        bfrag[h2] = *(const bf8*)rr4;
    }
}

// ---------------------------------------------------------------------------
// K1 (v9): v7's verified 16x16x32 layouts, but each wave owns TWO pixel
// groups (L = row h0, U = row h0+1, same 16 columns) and each A-frag load
// feeds TWO MFMAs -> per-pixel weight VMEM traffic HALVED (the v8 theory,
// tested without any new MFMA layout). Block = 256 thr = 4 waves = 128 px.
// TF 6x70 tile + OB as v7; LDS 68,124 B -> exactly 2 blocks/CU; grid 512.
// Per-pixel arithmetic and FMA order are bit-identical to v7.
// ---------------------------------------------------------------------------
__global__ __launch_bounds__(256, 2) void k_fused(const unsigned short* __restrict__ xT,
                                                  const unsigned short* __restrict__ wA2,
                                                  const unsigned short* __restrict__ Wal2,
                                                  const float* __restrict__ b_off,
                                                  const float* __restrict__ b_align,
                                                  float* __restrict__ wten) {
    __shared__ __align__(16) unsigned short TF[420 * 64];   // 6*70 entries * 128B
    __shared__ float OB[27 * 133];                          // 14,364 B

    int t = threadIdx.x, lane = t & 63, wv = t >> 6;        // wv 0..3
    int quad = lane >> 4, col = lane & 15;
    int bx = blockIdx.x;
    int b = bx >> 7;                        // 128 blocks per batch image
    int r = bx & 127;
    int h0 = (r >> 1) * 2;                  // 0,2,...,126
    int w0 = (r & 1) * 64;
    int pc = wv * 16 + col;                 // 0..63: column offset in block
    int wp = w0 + pc;
    int pxoL = pc, pxoU = pc + 64;          // OB columns for the two pixels
    int hL = h0, hU = h0 + 1;
    const unsigned short* xTb = xT + (size_t)b * HW * CC;
    const unsigned short* wl = Wal2 + lane * 8;        // + group*512 shorts

    // ---- stage 6x70 tile: 3360 16B chunks; source chunk pre-swizzled ----
#pragma unroll
    for (int u = 0; u < 14; u++) {
        int i = t + 256 * u;
        if (i < 3360) {
            int e = i >> 3, s = i & 7;
            int ty = e / 70, tx = e - ty * 70;
            int gy = min(max(h0 - 2 + ty, 0), 127);
            int gx = min(max(w0 - 3 + tx, 0), 127);
            int c = s ^ (e & 7);
            uint4 q = *(const uint4*)(xTb + ((size_t)((gy << 7) + gx)) * CC + c * 8);
            *(uint4*)(TF + i * 8) = q;
        }
    }
    __syncthreads();   // the ONLY barrier

    // ---- conv phase: 9 fixed taps; A-frags shared by both pixel rows ----
    {
        const bf8 zero = {0, 0, 0, 0, 0, 0, 0, 0};
        f4 aL0 = {0.f, 0.f, 0.f, 0.f}, aL1 = {0.f, 0.f, 0.f, 0.f};
        f4 aU0 = {0.f, 0.f, 0.f, 0.f}, aU1 = {0.f, 0.f, 0.f, 0.f};
#pragma unroll
        for (int tap = 0; tap < 9; tap++) {
            int dyt = tap / 3 - 1, dxt = tap - (tap / 3) * 3 - 1;
            int ws = wp + dxt;
            bool okw = (unsigned)ws < 128u;
            bool vL = ((unsigned)(hL + dyt) < 128u) && okw;
            bool vU = ((unsigned)(hU + dyt) < 128u) && okw;
            int eL = (dyt + 2) * 70 + pc + dxt + 3;   // row rr=0
            int eU = eL + 70;                          // row rr=1
            int sLq = quad ^ (eL & 7), sUq = quad ^ (eU & 7);
            bf8 b0L = *(const bf8*)(TF + eL * 64 + (sLq << 3));
            bf8 b1L = *(const bf8*)(TF + eL * 64 + ((sLq ^ 4) << 3));
            bf8 b0U = *(const bf8*)(TF + eU * 64 + (sUq << 3));
            bf8 b1U = *(const bf8*)(TF + eU * 64 + ((sUq ^ 4) << 3));
            b0L = vL ? b0L : zero;  b1L = vL ? b1L : zero;
            b0U = vU ? b0U : zero;  b1U = vU ? b1U : zero;
            const bf8 a00 = *(const bf8*)(wA2 + (((tap * 4 + 0) * 64 + lane) << 3));
            const bf8 a01 = *(const bf8*)(wA2 + (((tap * 4 + 1) * 64 + lane) << 3));
            const bf8 a10 = *(const bf8*)(wA2 + (((tap * 4 + 2) * 64 + lane) << 3));
            const bf8 a11 = *(const bf8*)(wA2 + (((tap * 4 + 3) * 64 + lane) << 3));
            aL0 = __builtin_amdgcn_mfma_f32_16x16x32_bf16(a00, b0L, aL0, 0, 0, 0);
            aL1 = __builtin_amdgcn_mfma_f32_16x16x32_bf16(a01, b0L, aL1, 0, 0, 0);
            aL0 = __builtin_amdgcn_mfma_f32_16x16x32_bf16(a10, b1L, aL0, 0, 0, 0);
            aL1 = __builtin_amdgcn_mfma_f32_16x16x32_bf16(a11, b1L, aL1, 0, 0, 0);
            aU0 = __builtin_amdgcn_mfma_f32_16x16x32_bf16(a00, b0U, aU0, 0, 0, 0);
            aU1 = __builtin_amdgcn_mfma_f32_16x16x32_bf16(a01, b0U, aU1, 0, 0, 0);
            aU0 = __builtin_amdgcn_mfma_f32_16x16x32_bf16(a10, b1U, aU0, 0, 0, 0);
            aU1 = __builtin_amdgcn_mfma_f32_16x16x32_bf16(a11, b1U, aU1, 0, 0, 0);
        }
        // redistribute (o, pixel) -> OB[o][pxo]; strictly intra-wave
#pragma unroll
        for (int i = 0; i < 4; i++) {
            int o0 = quad * 4 + i;                     // 0..15: never sigmoid
            OB[o0 * 133 + pxoL] = aL0[i] + b_off[o0];
            OB[o0 * 133 + pxoU] = aU0[i] + b_off[o0];
            int o1 = 16 + o0;
            if (o1 < 27) {
                float vL2 = aL1[i] + b_off[o1];
                float vU2 = aU1[i] + b_off[o1];
                if (o1 >= 18) {
                    vL2 = 2.f / (1.f + __expf(-vL2));
                    vU2 = 2.f / (1.f + __expf(-vU2));
                }
                OB[o1 * 133 + pxoL] = vL2;
                OB[o1 * 133 + pxoU] = vU2;
            }
        }
    }

    int hm2 = h0 - 2, hp3 = h0 + 3, wm3 = w0 - 3, wp66 = w0 + 66;

    f4 accL[4], accU[4];
#pragma unroll
    for (int mt = 0; mt < 4; mt++) {
        accL[mt] = (f4){0.f, 0.f, 0.f, 0.f};
        accU[mt] = (f4){0.f, 0.f, 0.f, 0.f};
    }

#pragma unroll
    for (int k = 0; k < 9; k++) {
        int k3 = k / 3, kx = k - 3 * k3;
        float dyL = OB[(2 * k) * 133 + pxoL], dxL = OB[(2 * k + 1) * 133 + pxoL];
        float mL  = OB[(18 + k) * 133 + pxoL];
        float dyU = OB[(2 * k) * 133 + pxoU], dxU = OB[(2 * k + 1) * 133 + pxoU];
        float mU  = OB[(18 + k) * 133 + pxoU];

        bf8 bfL[2], bfU[2];
        bilin_px(TF, xTb, dyL, dxL, mL, hL, wp, k3, kx, hm2, hp3, wm3, wp66, quad, bfL);
        bilin_px(TF, xTb, dyU, dxU, mU, hU, wp, k3, kx, hm2, hp3, wm3, wp66, quad, bfU);

#pragma unroll
        for (int h2 = 0; h2 < 2; h2++) {
#pragma unroll
            for (int mt = 0; mt < 4; mt++) {
                const bf8 a = *(const bf8*)(wl + (size_t)(((k * 2 + h2) * 4 + mt) * 512));
                accL[mt] = __builtin_amdgcn_mfma_f32_16x16x32_bf16(a, bfL[h2], accL[mt], 0, 0, 0);
                accU[mt] = __builtin_amdgcn_mfma_f32_16x16x32_bf16(a, bfU[h2], accU[mt], 0, 0, 0);
            }
        }
    }

    // ---- epilogue: bias + exp(sigmoid), both pixels ----
    float* wbL = wten + (size_t)b * CC * HW + (hL << 7) + wp;
    float* wbU = wten + (size_t)b * CC * HW + (hU << 7) + wp;
#pragma unroll
    for (int mt = 0; mt < 4; mt++)
#pragma unroll
        for (int i = 0; i < 4; i++) {
            int o = mt * 16 + quad * 4 + i;
            float uL = accL[mt][i] + b_align[o];
            wbL[(size_t)o * HW] = __expf(1.f / (1.f + __expf(-uL)));
            float uU = accU[mt][i] + b_align[o];
            wbU[(size_t)o * HW] = __expf(1.f / (1.f + __expf(-uU)));
        }
}

// ---------------------------------------------------------------------------
// K3: out = pool3s2(w*x)/pool3s2(w) (the /9 cancels; zero-pad taps drop out).
// ---------------------------------------------------------------------------
__global__ __launch_bounds__(256) void k_pool(const float* __restrict__ x,
                                              const float* __restrict__ wten,
                                              float* __restrict__ out) {
    int idx = blockIdx.x * 256 + threadIdx.x;
    int ow = idx & 63;
    int oh = (idx >> 6) & 63;
    int bc = idx >> 12;
    const float* wp = wten + (size_t)bc * HW;
    const float* xp = x + (size_t)bc * HW;
    float num = 0.f, den = 0.f;
#pragma unroll
    for (int iy = 0; iy < 3; iy++) {
        int y = 2 * oh + iy - 1;
        if ((unsigned)y >= 128u) continue;
#pragma unroll
        for (int ix = 0; ix < 3; ix++) {
            int xc = 2 * ow + ix - 1;
            if ((unsigned)xc >= 128u) continue;
            float wv = wp[y * 128 + xc];
            float xv = xp[y * 128 + xc];
            num = fmaf(wv, xv, num);
            den += wv;
        }
    }
    out[idx] = num / den;
}

// ---------------------------------------------------------------------------
extern "C" void kernel_launch(void* const* d_in, const int* in_sizes, int n_in,
                              void* d_out, int out_size, void* d_ws, size_t ws_size,
                              hipStream_t stream) {
    const float* x       = (const float*)d_in[0];
    const float* w_off   = (const float*)d_in[1];
    const float* b_off   = (const float*)d_in[2];
    const float* w_align = (const float*)d_in[3];
    const float* b_align = (const float*)d_in[4];
    float* out = (float*)d_out;

    // workspace layout (~25.3 MB):
    char* p = (char*)d_ws;
    float* wten = (float*)p;                  p += (size_t)BB * CC * HW * 4;  // 16.78 MB
    unsigned short* xT  = (unsigned short*)p; p += (size_t)BB * HW * CC * 2;  // 8.39 MB
    unsigned short* wA2 = (unsigned short*)p; p += 32 * 576 * 2;              // 36.9 KB
    unsigned short* Wal2 = (unsigned short*)p;                                // 73.7 KB

    k_prep_tx<<<dim3(1240), dim3(256), 0, stream>>>(x, w_off, w_align, xT, wA2, Wal2);
    k_fused<<<dim3(512), dim3(256), 0, stream>>>(xT, wA2, Wal2, b_off, b_align, wten);
    k_pool<<<dim3(4096), dim3(256), 0, stream>>>(x, wten, out);
}